// Round 18
// baseline (493.569 us; speedup 1.0000x reference)
//
#include <hip/hip_runtime.h>
#include <math.h>

#define T_STEPS 1024
#define FORECAST 30
#define BPB 8   // real batches per block; MFMA cols 8..15 = broadcast ghosts

typedef __attribute__((ext_vector_type(8))) _Float16 half8;   // 8 fp16 = 4 VGPRs
typedef __attribute__((ext_vector_type(4))) float f32x4;

__device__ __forceinline__ float rcp_fast(float v){ return __builtin_amdgcn_rcpf(v); }
__device__ __forceinline__ float exp2_fast(float v){ return __builtin_amdgcn_exp2f(v); }
__device__ __forceinline__ float med3(float a, float lo, float hi){ return __builtin_amdgcn_fmed3f(a, lo, hi); }
__device__ __forceinline__ f32x4 mfma16(half8 a, half8 b, f32x4 c){
    return __builtin_amdgcn_mfma_f32_16x16x32_f16(a, b, c, 0, 0, 0);
}

// "R10 done right": 512 blocks x 8 batches, 8 waves, 2 blocks/CU -> TWO
// independent barrier domains x 2 waves/SIMD each. R10 proved cross-domain
// stall-filling works (busy 49->65%) but paid 2x issue for ghost EW; here the
// ghosts are FREE:
//  - h stays 8 rows (1KB/buf); B-frag lanes l15 and l15+8 read the SAME LDS
//    address -> ghost columns via broadcast (no ghost storage, no conflicts).
//  - after MFMA each lane keeps ONE real state: sel=l15>>3 picks tile,
//    b7=l15&7 the batch -> per-CU EW issue == R16 (1024 real states/CU).
// Wave w owns j in [8w,8w+8) as 2 A-tiles sharing B-frags (2 ds_read_b128).
// EW: Pade-tanh form (6 trans, shortest chain; R17-validated numerics):
//   c' = (c*us + v*m)/(us*v); tanh via [7/6] Pade on clamp(c',4.6);
//   h = Pn * rcp((1+eO)*Pden).
// D layout: lane l holds D[m=l4*4+r][n=l15] => (batch=b7, j=w*8+sel*4+l4, gate=r).
// Branch-free t=0: h-buffer 1 pre-zeroed -> first MFMA reads h(-1)=0.
__global__ __launch_bounds__(512, 4)
void lstm_mfma_kernel(const float* __restrict__ x,      // [B, T]
                      const float* __restrict__ W_ih,   // [256]
                      const float* __restrict__ W_hh,   // [256, 64]
                      const float* __restrict__ b_ih,   // [256]
                      const float* __restrict__ b_hh,   // [256]
                      const float* __restrict__ fc_W,   // [30, 64]
                      const float* __restrict__ fc_b,   // [30]
                      float* __restrict__ out)          // [B, 30]
{
    __shared__ __align__(16) _Float16 hs[2][BPB][64];  // h fp16, swizzled, dbuf (2 KB)
    __shared__ float xs[2][64][BPB];                   // x chunks [buf][t&63][batch] (4 KB)

    const int tid = threadIdx.x;
    const int l   = tid & 63;
    const int w   = tid >> 6;        // 0..7
    const int l15 = l & 15;
    const int l4  = l >> 4;
    const int b7  = l15 & 7;         // real batch
    const int sel = l15 >> 3;        // which tile this lane keeps
    const int bb  = blockIdx.x * BPB;

    const float L2E  = 1.44269504088896f;
    const float TL2E = 2.88539008177793f;   // 2*log2(e)

    // ---- one-time: A-frags (2 tiles), gate-scales folded, identity k->j ----
    // lane supplies A[m=l15][k=kc*32+l4*8+e]; row m -> gate=m&3, joff=m>>2
    const int   ga   = l15 & 3;
    const float Srow = (ga == 2) ? TL2E : -L2E;   // tanh rows +2log2e, sigmoid -log2e
    half8 A[2][2];                   // [tile][k-chunk]
    #pragma unroll
    for (int T = 0; T < 2; ++T) {
        const int gc = ga*64 + w*8 + T*4 + (l15 >> 2);   // W_hh row (gate, j_out)
        #pragma unroll
        for (int kc = 0; kc < 2; ++kc) {
            const float* p = W_hh + gc*64 + kc*32 + l4*8;
            #pragma unroll
            for (int e = 0; e < 8; ++e)
                A[T][kc][e] = (_Float16)(p[e] * Srow);
        }
    }

    // per-lane x-weights/bias for BOTH tiles' D rows (gate=r, j=jT); EW keeps sel
    float wih[2][4], bia[2][4];
    #pragma unroll
    for (int T = 0; T < 2; ++T) {
        const int jT = w*8 + T*4 + l4;
        #pragma unroll
        for (int r = 0; r < 4; ++r) {
            const float S = (r == 2) ? TL2E : -L2E;
            const int   g = r*64 + jT;
            wih[T][r] = W_ih[g] * S;
            bia[T][r] = (b_ih[g] + b_hh[g]) * S;
        }
    }

    // LDS byte offsets (swizzle ^(b7<<4)); lanes l15 and l15+8 share rbase (broadcast)
    const int rbase = (b7*128 + l4*16) ^ (b7<<4);        // B-frag kc0; kc1 -> ^64
    const int jk    = w*8 + sel*4 + l4;                  // the state this lane keeps
    const int hwoff = (b7*128 + jk*2) ^ (b7<<4);         // b16 write
    char* const buf0 = (char*)hs;
    char* const buf1 = (char*)hs + 1024;

    // stage x chunk 0 (one store/thread: batch=w, t=l) + ZERO h-buffer 1
    xs[0][l][w] = x[(long long)(bb + w)*T_STEPS + l];
    if (tid < 256) ((unsigned*)hs)[256 + tid] = 0u;      // buf1 = bytes [1024,2048)
    __syncthreads();

    float cc = 0.f, hh = 0.f;
    float xv = xs[0][0][b7];

    #define LSTM_STEP(T_CUR, RBUF, WBUF)                                        \
    {                                                                           \
        const int t_ = (T_CUR);                                                 \
        const half8 b0 = *(const half8*)((RBUF) + rbase);                       \
        const half8 b1 = *(const half8*)((RBUF) + (rbase ^ 64));                \
        f32x4 acc0, acc1;                                                       \
        _Pragma("unroll")                                                       \
        for (int r = 0; r < 4; ++r) {                                           \
            acc0[r] = fmaf(xv, wih[0][r], bia[0][r]);                           \
            acc1[r] = fmaf(xv, wih[1][r], bia[1][r]);                           \
        }                                                                       \
        acc0 = mfma16(A[0][0], b0, acc0);                                       \
        acc1 = mfma16(A[1][0], b0, acc1);                                       \
        acc0 = mfma16(A[0][1], b1, acc0);                                       \
        acc1 = mfma16(A[1][1], b1, acc1);                                       \
        const int t1_ = t_ + 1;                                                 \
        const float xvn = xs[(t1_ >> 6) & 1][t1_ & 63][b7];                     \
        f32x4 a;                                                                \
        _Pragma("unroll")                                                       \
        for (int r = 0; r < 4; ++r) a[r] = sel ? acc1[r] : acc0[r];             \
        const float eI = exp2_fast(a[0]);                                       \
        const float eF = exp2_fast(a[1]);                                       \
        const float eG = exp2_fast(a[2]);                                       \
        const float eO = exp2_fast(a[3]);                                       \
        const float u  = 1.0f + eI;                                             \
        const float v  = 1.0f + eF;                                             \
        const float s  = 1.0f + eG;                                             \
        const float m  = s - 2.0f;                                              \
        const float us = u * s;                                                 \
        const float N  = fmaf(cc, us, v * m);                                   \
        cc = N * rcp_fast(us * v);                     /* true cell state */    \
        const float ct = med3(cc, -4.6f, 4.6f);                                 \
        const float z  = ct * ct;                                               \
        float q = fmaf(z, 21.0f, 1260.0f);                                      \
        q = fmaf(z, q, 10395.0f);                                               \
        const float Pn = ct * q;                                                \
        float r_ = z + 210.0f;                                                  \
        r_ = fmaf(z, r_, 4725.0f);                                              \
        r_ = fmaf(z, r_, 10395.0f);                                             \
        const float Dh = (eO + 1.0f) * r_;             /* merge o-gate rcp */   \
        hh = Pn * rcp_fast(Dh);                        /* h = o * tanh(c) */    \
        *(_Float16*)((WBUF) + hwoff) = (_Float16)hh;                            \
        xv = xvn;                                                               \
        __syncthreads();                                                        \
    }

    for (int t2 = 0; t2 < T_STEPS; t2 += 2) {
        if ((t2 & 63) == 0 && t2 + 64 < T_STEPS)   // stage next x chunk (1 store/thread)
            xs[((t2 >> 6) & 1) ^ 1][l][w] =
                x[(long long)(bb + w)*T_STEPS + t2 + 64 + l];
        LSTM_STEP(t2,     buf1, buf0);   // even t: read h(t-1) from buf1, write buf0
        LSTM_STEP(t2 + 1, buf0, buf1);   // odd  t: read from buf0, write buf1
    }
    #undef LSTM_STEP

    // ---- fused FC head (8 real batches) ----
    float* hsc = (float*)xs;            // reuse: hsc[8][64]
    hsc[b7*64 + jk] = hh;               // bijective over (b7, jk)
    __syncthreads();

    if (tid < BPB*FORECAST) {
        const int b = tid / FORECAST;
        const int f = tid % FORECAST;
        float a = fc_b[f];
        #pragma unroll
        for (int jj = 0; jj < 64; ++jj)
            a = fmaf(hsc[b*64 + jj], fc_W[f*64 + jj], a);
        out[(long long)(bb + b)*FORECAST + f] = a;
    }
}

extern "C" void kernel_launch(void* const* d_in, const int* in_sizes, int n_in,
                              void* d_out, int out_size, void* d_ws, size_t ws_size,
                              hipStream_t stream) {
    const float* x    = (const float*)d_in[0];
    const float* W_ih = (const float*)d_in[1];
    const float* W_hh = (const float*)d_in[2];
    const float* b_ih = (const float*)d_in[3];
    const float* b_hh = (const float*)d_in[4];
    const float* fc_W = (const float*)d_in[5];
    const float* fc_b = (const float*)d_in[6];
    float* out = (float*)d_out;

    // 4096 / 8 batches = 512 blocks -> 2 independent barrier domains per CU
    lstm_mfma_kernel<<<512, 512, 0, stream>>>(x, W_ih, W_hh, b_ih, b_hh, fc_W, fc_b, out);
}

// Round 19
// 357.837 us; speedup vs baseline: 1.3793x; 1.3793x over previous
//
#include <hip/hip_runtime.h>
#include <math.h>

#define T_STEPS 1024
#define FORECAST 30

typedef __attribute__((ext_vector_type(8))) _Float16 half8;    // 8 fp16 = 4 VGPRs
typedef __attribute__((ext_vector_type(2))) _Float16 half2v;   // 2 fp16 = 1 VGPR
typedef __attribute__((ext_vector_type(4))) float f32x4;
typedef __attribute__((ext_vector_type(2))) float f32x2;       // -> v_pk_*_f32

__device__ __forceinline__ float rcp_fast(float v){ return __builtin_amdgcn_rcpf(v); }
__device__ __forceinline__ float exp2_fast(float v){ return __builtin_amdgcn_exp2f(v); }
__device__ __forceinline__ float med3(float a, float lo, float hi){ return __builtin_amdgcn_fmed3f(a, lo, hi); }
__device__ __forceinline__ f32x4 mfma16(half8 a, half8 b, f32x4 c){
    return __builtin_amdgcn_mfma_f32_16x16x32_f16(a, b, c, 0, 0, 0);
}
__device__ __forceinline__ half2v pack_f16(float a, float b){
    return __builtin_bit_cast(half2v, __builtin_amdgcn_cvt_pkrtz(a, b));  // v_cvt_pkrtz_f16_f32
}

// Best measured structure (R17, 367.6us) + staging hoist. 18-round summary:
// - 8 waves x 2 j-tiles, 2 waves/SIMD is the measured optimum of the wave
//   matrix (1/SIMD=450us, 2/SIMD=368us, 4/SIMD=430-477us).
// - Two-barrier-domain variants regress x3 (R10/R11/R18): cross-domain fill
//   is real but its issue cost always exceeds the stall recovered.
// - Chain-shortening (Pade tanh, -1 trans stage) is perf-neutral (R16->R17);
//   kept for the slightly better timed dur.
// - Step floor ~970cyc = issue(~480/SIMD) + exchange chain (~550, partially
//   overlapped): barrier -> 16x ds_read_b128 burst -> MFMA -> EW -> write.
// EW per 2 states (f32x2 -> v_pk_*): i=1/u, f=1/v, g=(s-2)/s, o=1/(1+eO);
// c' = (c*us + v*m)/(us*v); tanh via [7/6] Pade on clamp(c',4.6);
// h = Pn * rcp((1+eO)*Pden).  12 trans + ~20 pk-VALU / wave-step.
// h slot p = w*8+l4*2+T <-> j=(p&~7)+(p&1)*4+((p&7)>>1) (perm baked into A).
// D layout: lane l holds D[m=l4*4+r][n=l15] => (batch=l15, j, gate=r) in-lane.
// Branch-free t=0: h-buffer 1 pre-zeroed -> first MFMA reads h(-1)=0.
__global__ __launch_bounds__(512, 1)
void lstm_mfma_kernel(const float* __restrict__ x,      // [B, T]
                      const float* __restrict__ W_ih,   // [256]
                      const float* __restrict__ W_hh,   // [256, 64]
                      const float* __restrict__ b_ih,   // [256]
                      const float* __restrict__ b_hh,   // [256]
                      const float* __restrict__ fc_W,   // [30, 64]
                      const float* __restrict__ fc_b,   // [30]
                      float* __restrict__ out)          // [B, 30]
{
    __shared__ __align__(16) _Float16 hs[2][16][64];   // h fp16, swizzled slots, dbuf
    __shared__ float xs[2][64][16];                    // x chunks [buf][t&63][batch]

    const int tid = threadIdx.x;
    const int l   = tid & 63;
    const int w   = tid >> 6;        // 0..7
    const int l15 = l & 15;
    const int l4  = l >> 4;
    const int bb  = blockIdx.x * 16;

    const float L2E  = 1.44269504088896f;
    const float TL2E = 2.88539008177793f;   // 2*log2(e)

    // ---- one-time: A-frags (2 tiles), gate-scales folded, j-perm baked ----
    const int   ga   = l15 & 3;
    const float Srow = (ga == 2) ? TL2E : -L2E;   // tanh rows +2log2e, sigmoid -log2e
    half8 A[2][2];                   // [tile][k-chunk]
    #pragma unroll
    for (int T = 0; T < 2; ++T) {
        const int gc = ga*64 + w*8 + T*4 + (l15 >> 2);   // W_hh row (gate, j_out)
        #pragma unroll
        for (int kc = 0; kc < 2; ++kc) {
            #pragma unroll
            for (int e = 0; e < 8; ++e) {
                const int p   = kc*32 + l4*8 + e;        // B slot
                const int jin = (p & ~7) + ((p & 1) << 2) + ((p & 7) >> 1);
                A[T][kc][e] = (_Float16)(W_hh[gc*64 + jin] * Srow);
            }
        }
    }

    // per-lane x-weights/bias for the 2 states this lane HOLDS (gate=r, j=jT)
    float wih[2][4], bia[2][4];
    #pragma unroll
    for (int T = 0; T < 2; ++T) {
        const int jT = w*8 + T*4 + l4;
        #pragma unroll
        for (int r = 0; r < 4; ++r) {
            const float S = (r == 2) ? TL2E : -L2E;
            const int   g = r*64 + jT;
            wih[T][r] = W_ih[g] * S;
            bia[T][r] = (b_ih[g] + b_hh[g]) * S;
        }
    }

    // LDS byte offsets (swizzle ^((b&7)<<4)):
    const int rbase = (l15*128 + l4*16) ^ ((l15&7)<<4);           // B-frag kc0; kc1 -> ^64
    const int hwoff = (l15*128 + w*16 + l4*4) ^ ((l15&7)<<4);     // b32 write, slots p0,p0+1
    char* const buf0 = (char*)hs;
    char* const buf1 = (char*)hs + 2048;

    // stage x chunk 0 + ZERO h-buffer 1 (first MFMA reads h(-1)=0)
    #pragma unroll
    for (int it = 0; it < 2; ++it) {
        const int b = w*2 + it;
        xs[0][l][b] = x[(long long)(bb + b)*T_STEPS + l];
    }
    ((unsigned*)hs)[512 + tid] = 0u;     // buf1 = bytes [2048,4096)
    __syncthreads();

    f32x2 cc = {0.f, 0.f}, hh01 = {0.f, 0.f};
    float xv = xs[0][0][l15];

    #define LSTM_STEP(T_CUR, RBUF, WBUF)                                        \
    {                                                                           \
        const half8 b0 = *(const half8*)((RBUF) + rbase);                       \
        const half8 b1 = *(const half8*)((RBUF) + (rbase ^ 64));                \
        f32x4 acc0, acc1;                                                       \
        _Pragma("unroll")                                                       \
        for (int r = 0; r < 4; ++r) {                                           \
            acc0[r] = fmaf(xv, wih[0][r], bia[0][r]);                           \
            acc1[r] = fmaf(xv, wih[1][r], bia[1][r]);                           \
        }                                                                       \
        acc0 = mfma16(A[0][0], b0, acc0);                                       \
        acc1 = mfma16(A[1][0], b0, acc1);                                       \
        acc0 = mfma16(A[0][1], b1, acc0);                                       \
        acc1 = mfma16(A[1][1], b1, acc1);                                       \
        const int t1_ = (T_CUR) + 1;                                            \
        const float xvn = xs[(t1_ >> 6) & 1][t1_ & 63][l15];                    \
        f32x2 eI, eF, eG, eO;                                                   \
        eI[0] = exp2_fast(acc0[0]); eI[1] = exp2_fast(acc1[0]);                 \
        eF[0] = exp2_fast(acc0[1]); eF[1] = exp2_fast(acc1[1]);                 \
        eG[0] = exp2_fast(acc0[2]); eG[1] = exp2_fast(acc1[2]);                 \
        eO[0] = exp2_fast(acc0[3]); eO[1] = exp2_fast(acc1[3]);                 \
        const f32x2 u  = eI + 1.0f;                                             \
        const f32x2 v  = eF + 1.0f;                                             \
        const f32x2 s  = eG + 1.0f;                                             \
        const f32x2 m  = s - 2.0f;                                              \
        const f32x2 us = u * s;                                                 \
        const f32x2 vm = v * m;                                                 \
        const f32x2 N  = cc * us + vm;                                          \
        const f32x2 Dd = us * v;                                                \
        f32x2 rD; rD[0] = rcp_fast(Dd[0]); rD[1] = rcp_fast(Dd[1]);             \
        cc = N * rD;                                   /* true cell state */    \
        f32x2 ct;                                                               \
        ct[0] = med3(cc[0], -4.6f, 4.6f);                                       \
        ct[1] = med3(cc[1], -4.6f, 4.6f);                                       \
        const f32x2 z = ct * ct;                                                \
        f32x2 q = z * 21.0f + 1260.0f;                                          \
        q = z * q + 10395.0f;                                                   \
        const f32x2 Pn = ct * q;                                                \
        f32x2 r_ = z + 210.0f;                                                  \
        r_ = z * r_ + 4725.0f;                                                  \
        r_ = z * r_ + 10395.0f;                                                 \
        const f32x2 Dh = (eO + 1.0f) * r_;             /* merge o-gate rcp */   \
        f32x2 rH; rH[0] = rcp_fast(Dh[0]); rH[1] = rcp_fast(Dh[1]);             \
        hh01 = Pn * rH;                                /* h = o * tanh(c) */    \
        *(half2v*)((WBUF) + hwoff) = pack_f16(hh01[0], hh01[1]);                \
        xv = xvn;                                                               \
        __syncthreads();                                                        \
    }

    // chunk loop: staging branch hoisted out of the steady-state step pairs.
    // Race-safety: the buffer written here was last READ two barriers ago
    // (final xvn prefetch of chunk c-1), so all waves have passed that point.
    for (int c = 0; c < T_STEPS/64; ++c) {
        if (c + 1 < T_STEPS/64) {
            #pragma unroll
            for (int it = 0; it < 2; ++it) {
                const int b = w*2 + it;
                xs[(c & 1) ^ 1][l][b] = x[(long long)(bb + b)*T_STEPS + (c+1)*64 + l];
            }
        }
        const int tbase = c*64;
        for (int p = 0; p < 32; ++p) {
            const int t2 = tbase + p*2;
            LSTM_STEP(t2,     buf1, buf0);   // even t: read h(t-1) from buf1, write buf0
            LSTM_STEP(t2 + 1, buf0, buf1);   // odd  t: read from buf0, write buf1
        }
    }
    #undef LSTM_STEP

    // ---- fused FC head ----
    float* hsc = (float*)xs;            // reuse: hsc[16][64], real-j indexing
    hsc[l15*64 + w*8 + l4]     = hh01[0];
    hsc[l15*64 + w*8 + 4 + l4] = hh01[1];
    __syncthreads();

    if (tid < 16*FORECAST) {
        const int b = tid / FORECAST;
        const int f = tid % FORECAST;
        float a = fc_b[f];
        #pragma unroll
        for (int jj = 0; jj < 64; ++jj)
            a = fmaf(hsc[b*64 + jj], fc_W[f*64 + jj], a);
        out[(long long)(bb + b)*FORECAST + f] = a;
    }
}

extern "C" void kernel_launch(void* const* d_in, const int* in_sizes, int n_in,
                              void* d_out, int out_size, void* d_ws, size_t ws_size,
                              hipStream_t stream) {
    const float* x    = (const float*)d_in[0];
    const float* W_ih = (const float*)d_in[1];
    const float* W_hh = (const float*)d_in[2];
    const float* b_ih = (const float*)d_in[3];
    const float* b_hh = (const float*)d_in[4];
    const float* fc_W = (const float*)d_in[5];
    const float* fc_b = (const float*)d_in[6];
    float* out = (float*)d_out;

    // 4096 / 16 batches per block = 256 blocks (1 per CU), 8 waves (2/SIMD)
    lstm_mfma_kernel<<<256, 512, 0, stream>>>(x, W_ih, W_hh, b_ih, b_hh, fc_W, fc_b, out);
}